// Round 14
// baseline (458.713 us; speedup 1.0000x reference)
//
#include <hip/hip_runtime.h>
#include <hip/hip_bf16.h>
#include <cstddef>
#include <cstdint>

#define NNODES 10000
#define NEDGES 160000
#define NH     128
#define NCOMBO 4
#define NMROWS (NCOMBO * NNODES)              // 40000 rows (combo-major)
#define FTILE  32                             // rows per conv/mlp tile
#define SSTR   136                            // bf16 LDS row stride (shorts) = 272B
#define FTILES (NMROWS / FTILE)               // 1250

typedef __attribute__((ext_vector_type(8))) short short8v;   // 8 bf16 (4 VGPR)
typedef __attribute__((ext_vector_type(4))) float f32x4;     // MFMA accumulator

// Branchless erf-gelu via Abramowitz-Stegun 7.1.26 (|erf err| <= 1.5e-7).
__device__ __forceinline__ float gelu_f(float v) {
    const float u  = v * 0.70710678118654752f;
    float au = __builtin_fabsf(u);
    au = fminf(au, 3.9192f);
    const float t  = __builtin_amdgcn_rcpf(__builtin_fmaf(0.3275911f, au, 1.0f));
    const float e  = __builtin_amdgcn_exp2f(au * au * -1.4426950408889634f);
    float p = __builtin_fmaf(1.061405429f, t, -1.453152027f);
    p = __builtin_fmaf(p, t, 1.421413741f);
    p = __builtin_fmaf(p, t, -0.284496736f);
    p = __builtin_fmaf(p, t, 0.254829592f);
    const float erf_abs = 1.0f - p * t * e;
    const float erf_s   = __builtin_copysignf(erf_abs, v);
    return 0.5f * v * (1.0f + erf_s);
}

__device__ __forceinline__ uint16_t f2bf_rne(float f) {
    const uint32_t x = __float_as_uint(f);
    return (uint16_t)((x + 0x7fffu + ((x >> 16) & 1u)) >> 16);
}
__device__ __forceinline__ uint32_t packbf2(float lo, float hi) {
    return ((uint32_t)f2bf_rne(hi) << 16) | (uint32_t)f2bf_rne(lo);
}
__device__ __forceinline__ float bflo(uint32_t u) { return __uint_as_float(u << 16); }
__device__ __forceinline__ float bfhi(uint32_t u) { return __uint_as_float(u & 0xffff0000u); }

// interleaved bf16 x-mirror: short index for (combo c, node n, channel ch)
__device__ __forceinline__ size_t xi2(int n, int ch, int c) {
    return (size_t)n * 512 + (ch >> 1) * 8 + c * 2 + (ch & 1);
}

// ========================= CSR build (by dst) ============================
__global__ __launch_bounds__(256) void hist_kernel(const int* __restrict__ ei,
                                                   int* __restrict__ deg) {
    const int e = blockIdx.x * 256 + threadIdx.x;
    if (e < NEDGES) atomicAdd(&deg[ei[NEDGES + e]], 1);
}

__global__ __launch_bounds__(1024) void scan_kernel(const int* __restrict__ deg,
                                                    int* __restrict__ off,
                                                    int* __restrict__ cursor) {
    __shared__ int ssum[1024];
    const int tid  = threadIdx.x;
    const int base = tid * 10;
    int loc[10];
    int s = 0;
    #pragma unroll
    for (int i = 0; i < 10; ++i) {
        const int idx = base + i;
        loc[i] = s;
        s += (idx < NNODES) ? deg[idx] : 0;
    }
    ssum[tid] = s;
    for (int d = 1; d < 1024; d <<= 1) {
        __syncthreads();
        const int t = (tid >= d) ? ssum[tid - d] : 0;
        __syncthreads();
        ssum[tid] += t;
    }
    __syncthreads();
    const int pref = ssum[tid] - s;
    #pragma unroll
    for (int i = 0; i < 10; ++i) {
        const int idx = base + i;
        if (idx < NNODES) { off[idx] = pref + loc[i]; cursor[idx] = pref + loc[i]; }
    }
    if (tid == 0) off[NNODES] = NEDGES;
}

__global__ __launch_bounds__(256) void scatter_kernel(const int* __restrict__ ei,
                                                      const float* __restrict__ ea,
                                                      int* __restrict__ cursor,
                                                      int* __restrict__ esrc,
                                                      float* __restrict__ ea_s) {
    const int e = blockIdx.x * 256 + threadIdx.x;
    if (e < NEDGES) {
        const int src = ei[e];
        const int dst = ei[NEDGES + e];
        const int pos = atomicAdd(&cursor[dst], 1);
        esrc[pos] = src;
        const float4* s = reinterpret_cast<const float4*>(ea + (size_t)e * 16);
        float4*       d = reinterpret_cast<float4*>(ea_s + (size_t)pos * 16);
        d[0] = s[0]; d[1] = s[1]; d[2] = s[2]; d[3] = s[3];
    }
}

// ============= bond embedding, precomputed once, bf16, CSR order =========
__global__ __launch_bounds__(256) void emb_kernel(
    const float* __restrict__ ea_s, const float* __restrict__ bW,
    const float* __restrict__ bb, uint32_t* __restrict__ embq)
{
    const int lane = threadIdx.x & 63;
    const int wid  = threadIdx.x >> 6;
    const int c0   = lane * 2;
    float2 wc[16];
    #pragma unroll
    for (int k = 0; k < 16; ++k)
        wc[k] = *reinterpret_cast<const float2*>(&bW[k * 128 + c0]);
    const float2 bbr = *reinterpret_cast<const float2*>(&bb[c0]);

    for (int j = blockIdx.x * 4 + wid; j < NEDGES; j += gridDim.x * 4) {
        const float4* eap = reinterpret_cast<const float4*>(ea_s + (size_t)j * 16);
        const float4 a0 = eap[0], a1 = eap[1], a2 = eap[2], a3 = eap[3];
        float s0 = bbr.x, s1 = bbr.y;
        s0 += a0.x*wc[0].x + a0.y*wc[1].x + a0.z*wc[2].x + a0.w*wc[3].x
            + a1.x*wc[4].x + a1.y*wc[5].x + a1.z*wc[6].x + a1.w*wc[7].x
            + a2.x*wc[8].x + a2.y*wc[9].x + a2.z*wc[10].x + a2.w*wc[11].x
            + a3.x*wc[12].x + a3.y*wc[13].x + a3.z*wc[14].x + a3.w*wc[15].x;
        s1 += a0.x*wc[0].y + a0.y*wc[1].y + a0.z*wc[2].y + a0.w*wc[3].y
            + a1.x*wc[4].y + a1.y*wc[5].y + a1.z*wc[6].y + a1.w*wc[7].y
            + a2.x*wc[8].y + a2.y*wc[9].y + a2.z*wc[10].y + a2.w*wc[11].y
            + a3.x*wc[12].y + a3.y*wc[13].y + a3.z*wc[14].y + a3.w*wc[15].y;
        embq[(size_t)j * 64 + lane] = packbf2(s0, s1);
    }
}

// === weight prep: transposed bf16 for 6 conv + mW1 (16384 ea) + mW2 (8192)
__global__ __launch_bounds__(256) void wtrans_kernel(
    const float* __restrict__ cW1, const float* __restrict__ cW2,
    const float* __restrict__ mW1, const float* __restrict__ mW2,
    short* __restrict__ wbf)
{
    const int gidx = blockIdx.x * 256 + threadIdx.x;   // 122880 total
    if (gidx >= 122880) return;
    if (gidx < 114688) {
        const int m  = gidx >> 14;                      // matrix 0..6
        const int el = gidx & 16383;
        const int n  = el >> 7;
        const int k  = el & 127;
        const float* W = (m < 3) ? (cW1 + m * 16384)
                       : (m < 6) ? (cW2 + (m - 3) * 16384) : mW1;
        wbf[(size_t)m * 16384 + n * 128 + k] = (short)f2bf_rne(W[k * 128 + n]);
    } else {
        const int el = gidx - 114688;                   // mW2: [128][64] -> [64][128]
        const int n  = el >> 7;
        const int k  = el & 127;
        wbf[114688 + n * 128 + k] = (short)f2bf_rne(mW2[k * 64 + n]);
    }
}

// === per-edge 4-combo mask, CSR order (exact fp32, layer-invariant) ======
__global__ __launch_bounds__(256) void emsk_kernel(
    const float* __restrict__ nm, const int* __restrict__ off,
    const int* __restrict__ esrc, float4* __restrict__ emsk)
{
    const int n = blockIdx.x * 256 + threadIdx.x;
    if (n >= NNODES) return;
    const float d0 = nm[0 * NNODES + n], d1 = nm[1 * NNODES + n];
    const float d2 = nm[2 * NNODES + n], d3 = nm[3 * NNODES + n];
    const int j1 = off[n + 1];
    for (int j = off[n]; j < j1; ++j) {
        const int s = esrc[j];
        emsk[j] = make_float4(nm[0 * NNODES + s] * d0, nm[1 * NNODES + s] * d1,
                              nm[2 * NNODES + s] * d2, nm[3 * NNODES + s] * d3);
    }
}

// === x -> interleaved bf16 mirror xbf2[n][pair][c] =======================
__global__ __launch_bounds__(256) void xcast_kernel(const float* __restrict__ x,
                                                    uint32_t* __restrict__ xbf2) {
    const int i = blockIdx.x * 256 + threadIdx.x;      // over NNODES*64
    if (i >= NNODES * 64) return;
    const int n = i >> 6, pair = i & 63;
    uint4 o;
    {
        const float2 v0 = *reinterpret_cast<const float2*>(&x[((size_t)0 * NNODES + n) * NH + pair * 2]);
        const float2 v1 = *reinterpret_cast<const float2*>(&x[((size_t)1 * NNODES + n) * NH + pair * 2]);
        const float2 v2 = *reinterpret_cast<const float2*>(&x[((size_t)2 * NNODES + n) * NH + pair * 2]);
        const float2 v3 = *reinterpret_cast<const float2*>(&x[((size_t)3 * NNODES + n) * NH + pair * 2]);
        o.x = packbf2(v0.x, v0.y); o.y = packbf2(v1.x, v1.y);
        o.z = packbf2(v2.x, v2.y); o.w = packbf2(v3.x, v3.y);
    }
    *reinterpret_cast<uint4*>(&xbf2[(size_t)i * 4]) = o;
}

// =============== message passing: 1 wave/node, interleaved gather ========
// hbf[c,n,:] = bf16( (1+eps)*x[c,n,:] + sum_j gelu(x[c,src]+emb_j)*emsk_j )
__global__ __launch_bounds__(256) void agg2_kernel(
    const uint32_t* __restrict__ xbf2,// [N][64][4] interleaved bf16 pairs
    const uint32_t* __restrict__ embq,// [E][64] packed bf16 pairs
    const float4* __restrict__ emsk,  // [E] per-combo masks
    const int*   __restrict__ off,    // [N+1]
    const int*   __restrict__ esrc,   // [E] CSR src
    const float* __restrict__ epsp, int layer,
    uint32_t* __restrict__ hbf)       // [4][N][64] planar packed bf16
{
    const int lane = threadIdx.x & 63;
    const int wid  = threadIdx.x >> 6;
    const float epv = 1.0f + epsp[layer];

    for (int n = blockIdx.x * 4 + wid; n < NNODES; n += gridDim.x * 4) {
        const int j0 = off[n], j1 = off[n + 1];
        float acc[4][2] = {{0.f,0.f},{0.f,0.f},{0.f,0.f},{0.f,0.f}};

        // 1-deep software pipeline (proven structure)
        uint32_t eq_c = 0; uint4 xq_c = {0,0,0,0}; float4 em_c = {0,0,0,0};
        if (j0 < j1) {
            const int s = esrc[j0];
            eq_c = embq[(size_t)j0 * 64 + lane];
            xq_c = *reinterpret_cast<const uint4*>(&xbf2[((size_t)s * 64 + lane) * 4]);
            em_c = emsk[j0];
        }
        for (int j = j0; j < j1; ++j) {
            const uint32_t eq = eq_c;
            const uint4  xq = xq_c;
            const float4 em = em_c;
            if (j + 1 < j1) {
                const int s = esrc[j + 1];
                eq_c = embq[(size_t)(j + 1) * 64 + lane];
                xq_c = *reinterpret_cast<const uint4*>(&xbf2[((size_t)s * 64 + lane) * 4]);
                em_c = emsk[j + 1];
            }
            const float e0 = bflo(eq);
            const float e1 = bfhi(eq);
            const uint32_t xs[4] = {xq.x, xq.y, xq.z, xq.w};
            const float    ms[4] = {em.x, em.y, em.z, em.w};
            #pragma unroll
            for (int c = 0; c < 4; ++c) {
                acc[c][0] += gelu_f(bflo(xs[c]) + e0) * ms[c];
                acc[c][1] += gelu_f(bfhi(xs[c]) + e1) * ms[c];
            }
        }
        const uint4 xn = *reinterpret_cast<const uint4*>(&xbf2[((size_t)n * 64 + lane) * 4]);
        const uint32_t xns[4] = {xn.x, xn.y, xn.z, xn.w};
        #pragma unroll
        for (int c = 0; c < 4; ++c) {
            const float o0 = epv * bflo(xns[c]) + acc[c][0];
            const float o1 = epv * bfhi(xns[c]) + acc[c][1];
            hbf[((size_t)c * NNODES + n) * 64 + lane] = packbf2(o0, o1);
        }
    }
}

// ============ fallback agg (fp32 gather, bf16 h out) =====================
__global__ __launch_bounds__(256) void agg_kernel(
    const float* __restrict__ xcur, const float* __restrict__ nm,
    const float* __restrict__ ea_s, const float* __restrict__ bW,
    const float* __restrict__ bb, const int* __restrict__ off,
    const int* __restrict__ esrc, const float* __restrict__ epsp, int layer,
    short* __restrict__ hbf_s)
{
    const int tid = threadIdx.x;
    const int h   = tid & 127;
    const int sub = tid >> 7;
    float wc[16];
    #pragma unroll
    for (int k = 0; k < 16; ++k) wc[k] = bW[k * 128 + h];
    const float bbr = bb[h];
    const float epv = 1.0f + epsp[layer];

    for (int n = blockIdx.x * 2 + sub; n < NNODES; n += gridDim.x * 2) {
        float acc0 = 0.f, acc1 = 0.f, acc2 = 0.f, acc3 = 0.f;
        const int j0 = off[n], j1 = off[n + 1];
        const float d0 = nm[0*NNODES+n], d1 = nm[1*NNODES+n];
        const float d2 = nm[2*NNODES+n], d3 = nm[3*NNODES+n];
        for (int j = j0; j < j1; ++j) {
            const int src = esrc[j];
            const float4* eap = reinterpret_cast<const float4*>(ea_s + (size_t)j * 16);
            const float4 a0 = eap[0], a1 = eap[1], a2 = eap[2], a3 = eap[3];
            float emb = bbr;
            emb += a0.x*wc[0] + a0.y*wc[1] + a0.z*wc[2] + a0.w*wc[3];
            emb += a1.x*wc[4] + a1.y*wc[5] + a1.z*wc[6] + a1.w*wc[7];
            emb += a2.x*wc[8] + a2.y*wc[9] + a2.z*wc[10] + a2.w*wc[11];
            emb += a3.x*wc[12] + a3.y*wc[13] + a3.z*wc[14] + a3.w*wc[15];
            const float m0 = nm[0*NNODES+src]*d0, m1 = nm[1*NNODES+src]*d1;
            const float m2 = nm[2*NNODES+src]*d2, m3 = nm[3*NNODES+src]*d3;
            acc0 += gelu_f(xcur[((size_t)0*NNODES+src)*NH+h] + emb) * m0;
            acc1 += gelu_f(xcur[((size_t)1*NNODES+src)*NH+h] + emb) * m1;
            acc2 += gelu_f(xcur[((size_t)2*NNODES+src)*NH+h] + emb) * m2;
            acc3 += gelu_f(xcur[((size_t)3*NNODES+src)*NH+h] + emb) * m3;
        }
        hbf_s[((size_t)0*NNODES+n)*NH+h] = (short)f2bf_rne(epv * xcur[((size_t)0*NNODES+n)*NH+h] + acc0);
        hbf_s[((size_t)1*NNODES+n)*NH+h] = (short)f2bf_rne(epv * xcur[((size_t)1*NNODES+n)*NH+h] + acc1);
        hbf_s[((size_t)2*NNODES+n)*NH+h] = (short)f2bf_rne(epv * xcur[((size_t)2*NNODES+n)*NH+h] + acc2);
        hbf_s[((size_t)3*NNODES+n)*NH+h] = (short)f2bf_rne(epv * xcur[((size_t)3*NNODES+n)*NH+h] + acc3);
    }
}

// -------------------------------------------------------------------------
// MFMA fused conv pair (round-12 proven LDS-staged version); epilogue emits
// fp32 xcur + interleaved bf16 mirror xbf2.
// Fragments (16x16x32 bf16): A/B lane l: 8 contig k at (l>>4)*8; row/col l&15.
// C/D: col = l&15, row = (l>>4)*4 + reg  [m89-verified].
// -------------------------------------------------------------------------
__global__ __launch_bounds__(256) void conv_mfma_kernel(
    const uint32_t* __restrict__ hb,  // [40000][64] packed bf16 (planar)
    const float* __restrict__ resid,  // [40000][128] fp32
    const short* __restrict__ W1t, const float* __restrict__ b1,
    const short* __restrict__ W2t, const float* __restrict__ b2,
    float* __restrict__ outp,         // [40000][128] fp32
    short* __restrict__ xb2)          // interleaved bf16 mirror
{
    __shared__ short sh[FTILE * SSTR];
    __shared__ short st[FTILE * SSTR];
    __shared__ short sw[128 * SSTR];

    const int tid  = threadIdx.x;
    const int lane = tid & 63;
    const int w    = tid >> 6;
    const int l15  = lane & 15;
    const int l4   = lane >> 4;
    const int colb = w * 32;
    const int row0 = blockIdx.x * FTILE;

    for (int i = tid; i < FTILE * 16; i += 256) {
        const int r = i >> 4, c = i & 15;
        *reinterpret_cast<uint4*>(&sh[r * SSTR + c * 8]) =
            *reinterpret_cast<const uint4*>(&hb[(size_t)(row0 + r) * 64 + c * 4]);
    }
    for (int i = tid; i < 128 * 16; i += 256) {
        const int r = i >> 4, c = i & 15;
        *reinterpret_cast<uint4*>(&sw[r * SSTR + c * 8]) =
            *reinterpret_cast<const uint4*>(&W1t[r * 128 + c * 8]);
    }
    __syncthreads();

    f32x4 a00 = {0,0,0,0}, a01 = {0,0,0,0}, a10 = {0,0,0,0}, a11 = {0,0,0,0};
    #pragma unroll
    for (int s = 0; s < 4; ++s) {
        const int ko = s * 32 + l4 * 8;
        short8v fa0 = *reinterpret_cast<const short8v*>(&sh[(l15)      * SSTR + ko]);
        short8v fa1 = *reinterpret_cast<const short8v*>(&sh[(16 + l15) * SSTR + ko]);
        short8v fb0 = *reinterpret_cast<const short8v*>(&sw[(colb + l15)      * SSTR + ko]);
        short8v fb1 = *reinterpret_cast<const short8v*>(&sw[(colb + 16 + l15) * SSTR + ko]);
        a00 = __builtin_amdgcn_mfma_f32_16x16x32_bf16(fa0, fb0, a00, 0, 0, 0);
        a01 = __builtin_amdgcn_mfma_f32_16x16x32_bf16(fa0, fb1, a01, 0, 0, 0);
        a10 = __builtin_amdgcn_mfma_f32_16x16x32_bf16(fa1, fb0, a10, 0, 0, 0);
        a11 = __builtin_amdgcn_mfma_f32_16x16x32_bf16(fa1, fb1, a11, 0, 0, 0);
    }

    {
        const float bv0 = b1[colb + l15];
        const float bv1 = b1[colb + 16 + l15];
        #pragma unroll
        for (int j = 0; j < 4; ++j) {
            const int r0 = l4 * 4 + j;
            st[r0 * SSTR + colb + l15]             = (short)f2bf_rne(gelu_f(a00[j] + bv0));
            st[r0 * SSTR + colb + 16 + l15]        = (short)f2bf_rne(gelu_f(a01[j] + bv1));
            st[(16 + r0) * SSTR + colb + l15]      = (short)f2bf_rne(gelu_f(a10[j] + bv0));
            st[(16 + r0) * SSTR + colb + 16 + l15] = (short)f2bf_rne(gelu_f(a11[j] + bv1));
        }
    }
    __syncthreads();

    for (int i = tid; i < 128 * 16; i += 256) {
        const int r = i >> 4, c = i & 15;
        *reinterpret_cast<uint4*>(&sw[r * SSTR + c * 8]) =
            *reinterpret_cast<const uint4*>(&W2t[r * 128 + c * 8]);
    }
    __syncthreads();

    a00 = {0,0,0,0}; a01 = {0,0,0,0}; a10 = {0,0,0,0}; a11 = {0,0,0,0};
    #pragma unroll
    for (int s = 0; s < 4; ++s) {
        const int ko = s * 32 + l4 * 8;
        short8v fa0 = *reinterpret_cast<const short8v*>(&st[(l15)      * SSTR + ko]);
        short8v fa1 = *reinterpret_cast<const short8v*>(&st[(16 + l15) * SSTR + ko]);
        short8v fb0 = *reinterpret_cast<const short8v*>(&sw[(colb + l15)      * SSTR + ko]);
        short8v fb1 = *reinterpret_cast<const short8v*>(&sw[(colb + 16 + l15) * SSTR + ko]);
        a00 = __builtin_amdgcn_mfma_f32_16x16x32_bf16(fa0, fb0, a00, 0, 0, 0);
        a01 = __builtin_amdgcn_mfma_f32_16x16x32_bf16(fa0, fb1, a01, 0, 0, 0);
        a10 = __builtin_amdgcn_mfma_f32_16x16x32_bf16(fa1, fb0, a10, 0, 0, 0);
        a11 = __builtin_amdgcn_mfma_f32_16x16x32_bf16(fa1, fb1, a11, 0, 0, 0);
    }

    {
        const float bv0 = b2[colb + l15];
        const float bv1 = b2[colb + 16 + l15];
        const int c00 = colb + l15;
        const int c01 = colb + 16 + l15;
        #pragma unroll
        for (int j = 0; j < 4; ++j) {
            const int r0 = row0 + l4 * 4 + j;
            const int r1 = r0 + 16;
            const int cb0 = r0 / NNODES, nn0 = r0 - cb0 * NNODES;
            const int cb1 = r1 / NNODES, nn1 = r1 - cb1 * NNODES;
            const size_t o00 = (size_t)r0 * NH + c00;
            const size_t o01 = (size_t)r0 * NH + c01;
            const size_t o10 = (size_t)r1 * NH + c00;
            const size_t o11 = (size_t)r1 * NH + c01;
            const float v00 = resid[o00] + gelu_f(a00[j] + bv0);
            const float v01 = resid[o01] + gelu_f(a01[j] + bv1);
            const float v10 = resid[o10] + gelu_f(a10[j] + bv0);
            const float v11 = resid[o11] + gelu_f(a11[j] + bv1);
            outp[o00] = v00; xb2[xi2(nn0, c00, cb0)] = (short)f2bf_rne(v00);
            outp[o01] = v01; xb2[xi2(nn0, c01, cb0)] = (short)f2bf_rne(v01);
            outp[o10] = v10; xb2[xi2(nn1, c00, cb1)] = (short)f2bf_rne(v10);
            outp[o11] = v11; xb2[xi2(nn1, c01, cb1)] = (short)f2bf_rne(v11);
        }
    }
}

// -------------------------------------------------------------------------
// MFMA fused final MLP (round-12 structure, staged from fp32 xcur).
// -------------------------------------------------------------------------
__global__ __launch_bounds__(256) void mlp_mfma_kernel(
    const float* __restrict__ x,      // [40000][128] fp32
    const short* __restrict__ W1t, const float* __restrict__ b1,
    const short* __restrict__ W2t,    // [64 n][128 k] bf16
    const float* __restrict__ b2,     // [64]
    const float* __restrict__ nm,     // [40000]
    float* __restrict__ oacc)         // [256]
{
    __shared__ short sx[FTILE * SSTR];
    __shared__ short st[FTILE * SSTR];
    __shared__ short sw[128 * SSTR];
    __shared__ float sacc[256];

    const int tid  = threadIdx.x;
    const int lane = tid & 63;
    const int w    = tid >> 6;
    const int l15  = lane & 15;
    const int l4   = lane >> 4;
    const int colb = w * 32;
    const int row0 = blockIdx.x * FTILE;

    sacc[tid] = 0.0f;

    for (int i = tid; i < FTILE * 32; i += 256) {
        const int r = i >> 5, q = i & 31;
        const float4 v = reinterpret_cast<const float4*>(x + (size_t)(row0 + r) * NH)[q];
        uint2 pk;
        pk.x = packbf2(v.x, v.y);
        pk.y = packbf2(v.z, v.w);
        *reinterpret_cast<uint2*>(&sx[r * SSTR + q * 4]) = pk;
    }
    for (int i = tid; i < 128 * 16; i += 256) {
        const int r = i >> 4, c = i & 15;
        *reinterpret_cast<uint4*>(&sw[r * SSTR + c * 8]) =
            *reinterpret_cast<const uint4*>(&W1t[r * 128 + c * 8]);
    }
    __syncthreads();

    f32x4 a00 = {0,0,0,0}, a01 = {0,0,0,0}, a10 = {0,0,0,0}, a11 = {0,0,0,0};
    #pragma unroll
    for (int s = 0; s < 4; ++s) {
        const int ko = s * 32 + l4 * 8;
        short8v fa0 = *reinterpret_cast<const short8v*>(&sx[(l15)      * SSTR + ko]);
        short8v fa1 = *reinterpret_cast<const short8v*>(&sx[(16 + l15) * SSTR + ko]);
        short8v fb0 = *reinterpret_cast<const short8v*>(&sw[(colb + l15)      * SSTR + ko]);
        short8v fb1 = *reinterpret_cast<const short8v*>(&sw[(colb + 16 + l15) * SSTR + ko]);
        a00 = __builtin_amdgcn_mfma_f32_16x16x32_bf16(fa0, fb0, a00, 0, 0, 0);
        a01 = __builtin_amdgcn_mfma_f32_16x16x32_bf16(fa0, fb1, a01, 0, 0, 0);
        a10 = __builtin_amdgcn_mfma_f32_16x16x32_bf16(fa1, fb0, a10, 0, 0, 0);
        a11 = __builtin_amdgcn_mfma_f32_16x16x32_bf16(fa1, fb1, a11, 0, 0, 0);
    }

    {
        const float bv0 = b1[colb + l15];
        const float bv1 = b1[colb + 16 + l15];
        #pragma unroll
        for (int j = 0; j < 4; ++j) {
            const int r0 = l4 * 4 + j;
            st[r0 * SSTR + colb + l15]             = (short)f2bf_rne(fmaxf(a00[j] + bv0, 0.f));
            st[r0 * SSTR + colb + 16 + l15]        = (short)f2bf_rne(fmaxf(a01[j] + bv1, 0.f));
            st[(16 + r0) * SSTR + colb + l15]      = (short)f2bf_rne(fmaxf(a10[j] + bv0, 0.f));
            st[(16 + r0) * SSTR + colb + 16 + l15] = (short)f2bf_rne(fmaxf(a11[j] + bv1, 0.f));
        }
    }
    __syncthreads();

    for (int i = tid; i < 64 * 16; i += 256) {
        const int r = i >> 4, c = i & 15;
        *reinterpret_cast<uint4*>(&sw[r * SSTR + c * 8]) =
            *reinterpret_cast<const uint4*>(&W2t[r * 128 + c * 8]);
    }
    __syncthreads();

    const int colb2 = w * 16;
    f32x4 c0f = {0,0,0,0}, c1f = {0,0,0,0};
    #pragma unroll
    for (int s = 0; s < 4; ++s) {
        const int ko = s * 32 + l4 * 8;
        short8v fa0 = *reinterpret_cast<const short8v*>(&st[(l15)      * SSTR + ko]);
        short8v fa1 = *reinterpret_cast<const short8v*>(&st[(16 + l15) * SSTR + ko]);
        short8v fb  = *reinterpret_cast<const short8v*>(&sw[(colb2 + l15) * SSTR + ko]);
        c0f = __builtin_amdgcn_mfma_f32_16x16x32_bf16(fa0, fb, c0f, 0, 0, 0);
        c1f = __builtin_amdgcn_mfma_f32_16x16x32_bf16(fa1, fb, c1f, 0, 0, 0);
    }

    {
        const float bv = b2[colb2 + l15];
        #pragma unroll
        for (int j = 0; j < 4; ++j) {
            const int gr0 = row0 + l4 * 4 + j;
            const int gr1 = gr0 + 16;
            const float w0 = nm[gr0];
            const float w1 = nm[gr1];
            const int cb0 = gr0 / NNODES;
            const int cb1 = gr1 / NNODES;
            atomicAdd(&sacc[cb0 * 64 + colb2 + l15], (c0f[j] + bv) * w0);
            atomicAdd(&sacc[cb1 * 64 + colb2 + l15], (c1f[j] + bv) * w1);
        }
    }

    __syncthreads();
    atomicAdd(&oacc[tid], sacc[tid]);
}

// -------------------------------------------------------------------------
__global__ __launch_bounds__(256) void final_kernel(
    const float* __restrict__ acc, const float* __restrict__ nm,
    float* __restrict__ outp)
{
    const int tid  = threadIdx.x;
    const int c    = tid >> 6;
    const int lane = tid & 63;
    float s = 0.f;
    for (int n = lane; n < NNODES; n += 64) s += nm[c * NNODES + n];
    #pragma unroll
    for (int off = 32; off > 0; off >>= 1) s += __shfl_down(s, off, 64);
    const float denom = __shfl(s, 0, 64);
    outp[tid] = acc[tid] / denom;
}

extern "C" void kernel_launch(void* const* d_in, const int* in_sizes, int n_in,
                              void* d_out, int out_size, void* d_ws, size_t ws_size,
                              hipStream_t stream) {
    const float* x    = (const float*)d_in[0];
    const float* nm   = (const float*)d_in[1];
    const float* ea   = (const float*)d_in[2];
    const float* bW   = (const float*)d_in[3];
    const float* bb   = (const float*)d_in[4];
    const float* cW1  = (const float*)d_in[5];
    const float* cb1  = (const float*)d_in[6];
    const float* cW2  = (const float*)d_in[7];
    const float* cb2  = (const float*)d_in[8];
    const float* eps  = (const float*)d_in[9];
    const float* mW1  = (const float*)d_in[10];
    const float* mb1  = (const float*)d_in[11];
    const float* mW2  = (const float*)d_in[12];
    const float* mb2  = (const float*)d_in[13];
    const int*   ei   = (const int*)d_in[14];

    float* ws = (float*)d_ws;
    const bool big = ws_size >= (size_t)23230600ULL * 4ULL;   // ~93 MB

    if (big) {
        float*    xcur = ws;                           // 5,120,000
        float*    oacc = ws + 5120000;                 // 256
        uint32_t* hbf  = (uint32_t*)(ws + 5120512);    // 2,560,000 uints
        uint32_t* xbf2 = (uint32_t*)(ws + 7680512);    // 2,560,000 uints (interleaved)
        float*    ea_s = ws + 10240512;                // 2,560,000 (dead after emb)
        short*    wbf  = (short*)ea_s;                 // 122,880 bf16 (aliases ea_s)
        float4*   emsk = (float4*)(ea_s + 61440);      // 160,000 float4 (aliases ea_s)
        uint32_t* embq = (uint32_t*)(ws + 12800512);   // 10,240,000 uints
        int*      ib   = (int*)(ws + 23040512);
        int* off = ib; int* cur = ib + 10002; int* deg = ib + 20002;
        int* esrc = ib + 30002;

        hipMemsetAsync(deg, 0, 10000 * 4, stream);
        hist_kernel<<<(NEDGES + 255) / 256, 256, 0, stream>>>(ei, deg);
        scan_kernel<<<1, 1024, 0, stream>>>(deg, off, cur);
        scatter_kernel<<<(NEDGES + 255) / 256, 256, 0, stream>>>(ei, ea, cur, esrc, ea_s);
        emb_kernel<<<10000, 256, 0, stream>>>(ea_s, bW, bb, embq);
        // ea_s region dead after emb: wbf + emsk may alias it now
        wtrans_kernel<<<480, 256, 0, stream>>>(cW1, cW2, mW1, mW2, wbf);
        emsk_kernel<<<(NNODES + 255) / 256, 256, 0, stream>>>(nm, off, esrc, emsk);
        xcast_kernel<<<2500, 256, 0, stream>>>(x, xbf2);

        for (int l = 0; l < 3; ++l) {
            const float* resid = (l == 0) ? x : xcur;
            agg2_kernel<<<2500, 256, 0, stream>>>(xbf2, embq, emsk, off, esrc,
                                                  eps, l, hbf);
            conv_mfma_kernel<<<FTILES, 256, 0, stream>>>(hbf, resid,
                wbf + (size_t)l * 16384, cb1 + l * 128,
                wbf + (size_t)(3 + l) * 16384, cb2 + l * 128,
                xcur, (short*)xbf2);
        }
        hipMemsetAsync(oacc, 0, 256 * 4, stream);
        mlp_mfma_kernel<<<FTILES, 256, 0, stream>>>(xcur, wbf + 98304, mb1,
                                                    wbf + 114688, mb2, nm, oacc);
        final_kernel<<<1, 256, 0, stream>>>(oacc, nm, (float*)d_out);
    } else {
        // fallback (~52.3 MB): fp32-gather agg + MFMA conv/mlp (xbf2 unused reads)
        float*    xcur = ws;                           // 5,120,000
        float*    oacc = ws + 5120000;                 // 256
        uint32_t* hbf  = (uint32_t*)(ws + 5120512);    // 2,560,000 uints
        uint32_t* xbf2 = (uint32_t*)(ws + 7680512);    // 2,560,000 uints
        float*    ea_s = ws + 10240512;                // 2,560,000
        int*      ib   = (int*)(ws + 12800512);
        int* off = ib; int* cur = ib + 10002; int* deg = ib + 20002;
        int* esrc = ib + 30002;
        short* wbf = (short*)(ib + 190004);            // 122,880 shorts

        hipMemcpyAsync(xcur, x, (size_t)5120000 * 4, hipMemcpyDeviceToDevice, stream);
        hipMemsetAsync(deg, 0, 10000 * 4, stream);
        hist_kernel<<<(NEDGES + 255) / 256, 256, 0, stream>>>(ei, deg);
        scan_kernel<<<1, 1024, 0, stream>>>(deg, off, cur);
        scatter_kernel<<<(NEDGES + 255) / 256, 256, 0, stream>>>(ei, ea, cur, esrc, ea_s);
        wtrans_kernel<<<480, 256, 0, stream>>>(cW1, cW2, mW1, mW2, wbf);

        for (int l = 0; l < 3; ++l) {
            const float* resid = (l == 0) ? x : xcur;
            agg_kernel<<<2500, 256, 0, stream>>>(xcur, nm, ea_s, bW, bb, off, esrc,
                                                 eps, l, (short*)hbf);
            conv_mfma_kernel<<<FTILES, 256, 0, stream>>>(hbf, resid,
                wbf + (size_t)l * 16384, cb1 + l * 128,
                wbf + (size_t)(3 + l) * 16384, cb2 + l * 128,
                xcur, (short*)xbf2);
        }
        hipMemsetAsync(oacc, 0, 256 * 4, stream);
        mlp_mfma_kernel<<<FTILES, 256, 0, stream>>>(xcur, wbf + 98304, mb1,
                                                    wbf + 114688, mb2, nm, oacc);
        final_kernel<<<1, 256, 0, stream>>>(oacc, nm, (float*)d_out);
    }
}

// Round 15
// 437.396 us; speedup vs baseline: 1.0487x; 1.0487x over previous
//
#include <hip/hip_runtime.h>
#include <hip/hip_bf16.h>
#include <cstddef>
#include <cstdint>

#define NNODES 10000
#define NEDGES 160000
#define NH     128
#define NCOMBO 4
#define NMROWS (NCOMBO * NNODES)              // 40000 rows (combo-major)
#define FTILE  32                             // rows per conv/mlp tile
#define SSTR   136                            // bf16 LDS row stride (shorts) = 272B
#define FTILES (NMROWS / FTILE)               // 1250

typedef __attribute__((ext_vector_type(8))) short short8v;   // 8 bf16 (4 VGPR)
typedef __attribute__((ext_vector_type(4))) float f32x4;     // MFMA accumulator

// Branchless erf-gelu via Abramowitz-Stegun 7.1.26 (|erf err| <= 1.5e-7).
__device__ __forceinline__ float gelu_f(float v) {
    const float u  = v * 0.70710678118654752f;
    float au = __builtin_fabsf(u);
    au = fminf(au, 3.9192f);
    const float t  = __builtin_amdgcn_rcpf(__builtin_fmaf(0.3275911f, au, 1.0f));
    const float e  = __builtin_amdgcn_exp2f(au * au * -1.4426950408889634f);
    float p = __builtin_fmaf(1.061405429f, t, -1.453152027f);
    p = __builtin_fmaf(p, t, 1.421413741f);
    p = __builtin_fmaf(p, t, -0.284496736f);
    p = __builtin_fmaf(p, t, 0.254829592f);
    const float erf_abs = 1.0f - p * t * e;
    const float erf_s   = __builtin_copysignf(erf_abs, v);
    return 0.5f * v * (1.0f + erf_s);
}

__device__ __forceinline__ uint16_t f2bf_rne(float f) {
    const uint32_t x = __float_as_uint(f);
    return (uint16_t)((x + 0x7fffu + ((x >> 16) & 1u)) >> 16);
}
__device__ __forceinline__ uint32_t packbf2(float lo, float hi) {
    return ((uint32_t)f2bf_rne(hi) << 16) | (uint32_t)f2bf_rne(lo);
}
__device__ __forceinline__ float bflo(uint32_t u) { return __uint_as_float(u << 16); }
__device__ __forceinline__ float bfhi(uint32_t u) { return __uint_as_float(u & 0xffff0000u); }

// ========================= CSR build (by dst) ============================
__global__ __launch_bounds__(256) void hist_kernel(const int* __restrict__ ei,
                                                   int* __restrict__ deg) {
    const int e = blockIdx.x * 256 + threadIdx.x;
    if (e < NEDGES) atomicAdd(&deg[ei[NEDGES + e]], 1);
}

__global__ __launch_bounds__(1024) void scan_kernel(const int* __restrict__ deg,
                                                    int* __restrict__ off,
                                                    int* __restrict__ cursor) {
    __shared__ int ssum[1024];
    const int tid  = threadIdx.x;
    const int base = tid * 10;
    int loc[10];
    int s = 0;
    #pragma unroll
    for (int i = 0; i < 10; ++i) {
        const int idx = base + i;
        loc[i] = s;
        s += (idx < NNODES) ? deg[idx] : 0;
    }
    ssum[tid] = s;
    for (int d = 1; d < 1024; d <<= 1) {
        __syncthreads();
        const int t = (tid >= d) ? ssum[tid - d] : 0;
        __syncthreads();
        ssum[tid] += t;
    }
    __syncthreads();
    const int pref = ssum[tid] - s;
    #pragma unroll
    for (int i = 0; i < 10; ++i) {
        const int idx = base + i;
        if (idx < NNODES) { off[idx] = pref + loc[i]; cursor[idx] = pref + loc[i]; }
    }
    if (tid == 0) off[NNODES] = NEDGES;
}

__global__ __launch_bounds__(256) void scatter_kernel(const int* __restrict__ ei,
                                                      const float* __restrict__ ea,
                                                      int* __restrict__ cursor,
                                                      int* __restrict__ esrc,
                                                      float* __restrict__ ea_s) {
    const int e = blockIdx.x * 256 + threadIdx.x;
    if (e < NEDGES) {
        const int src = ei[e];
        const int dst = ei[NEDGES + e];
        const int pos = atomicAdd(&cursor[dst], 1);
        esrc[pos] = src;
        const float4* s = reinterpret_cast<const float4*>(ea + (size_t)e * 16);
        float4*       d = reinterpret_cast<float4*>(ea_s + (size_t)pos * 16);
        d[0] = s[0]; d[1] = s[1]; d[2] = s[2]; d[3] = s[3];
    }
}

// ============= bond embedding, precomputed once, bf16, CSR order =========
__global__ __launch_bounds__(256) void emb_kernel(
    const float* __restrict__ ea_s, const float* __restrict__ bW,
    const float* __restrict__ bb, uint32_t* __restrict__ embq)
{
    const int lane = threadIdx.x & 63;
    const int wid  = threadIdx.x >> 6;
    const int c0   = lane * 2;
    float2 wc[16];
    #pragma unroll
    for (int k = 0; k < 16; ++k)
        wc[k] = *reinterpret_cast<const float2*>(&bW[k * 128 + c0]);
    const float2 bbr = *reinterpret_cast<const float2*>(&bb[c0]);

    for (int j = blockIdx.x * 4 + wid; j < NEDGES; j += gridDim.x * 4) {
        const float4* eap = reinterpret_cast<const float4*>(ea_s + (size_t)j * 16);
        const float4 a0 = eap[0], a1 = eap[1], a2 = eap[2], a3 = eap[3];
        float s0 = bbr.x, s1 = bbr.y;
        s0 += a0.x*wc[0].x + a0.y*wc[1].x + a0.z*wc[2].x + a0.w*wc[3].x
            + a1.x*wc[4].x + a1.y*wc[5].x + a1.z*wc[6].x + a1.w*wc[7].x
            + a2.x*wc[8].x + a2.y*wc[9].x + a2.z*wc[10].x + a2.w*wc[11].x
            + a3.x*wc[12].x + a3.y*wc[13].x + a3.z*wc[14].x + a3.w*wc[15].x;
        s1 += a0.x*wc[0].y + a0.y*wc[1].y + a0.z*wc[2].y + a0.w*wc[3].y
            + a1.x*wc[4].y + a1.y*wc[5].y + a1.z*wc[6].y + a1.w*wc[7].y
            + a2.x*wc[8].y + a2.y*wc[9].y + a2.z*wc[10].y + a2.w*wc[11].y
            + a3.x*wc[12].y + a3.y*wc[13].y + a3.z*wc[14].y + a3.w*wc[15].y;
        embq[(size_t)j * 64 + lane] = packbf2(s0, s1);
    }
}

// === weight prep: transposed bf16 for 6 conv + mW1 (16384 ea) + mW2 (8192)
__global__ __launch_bounds__(256) void wtrans_kernel(
    const float* __restrict__ cW1, const float* __restrict__ cW2,
    const float* __restrict__ mW1, const float* __restrict__ mW2,
    short* __restrict__ wbf)
{
    const int gidx = blockIdx.x * 256 + threadIdx.x;   // 122880 total
    if (gidx >= 122880) return;
    if (gidx < 114688) {
        const int m  = gidx >> 14;                      // matrix 0..6
        const int el = gidx & 16383;
        const int n  = el >> 7;
        const int k  = el & 127;
        const float* W = (m < 3) ? (cW1 + m * 16384)
                       : (m < 6) ? (cW2 + (m - 3) * 16384) : mW1;
        wbf[(size_t)m * 16384 + n * 128 + k] = (short)f2bf_rne(W[k * 128 + n]);
    } else {
        const int el = gidx - 114688;                   // mW2: [128][64] -> [64][128]
        const int n  = el >> 7;
        const int k  = el & 127;
        wbf[114688 + n * 128 + k] = (short)f2bf_rne(mW2[k * 64 + n]);
    }
}

// === per-edge 4-combo mask, CSR order (exact fp32, layer-invariant) ======
__global__ __launch_bounds__(256) void emsk_kernel(
    const float* __restrict__ nm, const int* __restrict__ off,
    const int* __restrict__ esrc, float4* __restrict__ emsk)
{
    const int n = blockIdx.x * 256 + threadIdx.x;
    if (n >= NNODES) return;
    const float d0 = nm[0 * NNODES + n], d1 = nm[1 * NNODES + n];
    const float d2 = nm[2 * NNODES + n], d3 = nm[3 * NNODES + n];
    const int j1 = off[n + 1];
    for (int j = off[n]; j < j1; ++j) {
        const int s = esrc[j];
        emsk[j] = make_float4(nm[0 * NNODES + s] * d0, nm[1 * NNODES + s] * d1,
                              nm[2 * NNODES + s] * d2, nm[3 * NNODES + s] * d3);
    }
}

// === x -> packed bf16 planar mirror ======================================
__global__ __launch_bounds__(256) void xcast_kernel(const float* __restrict__ x,
                                                    uint32_t* __restrict__ xbf) {
    const int i = blockIdx.x * 256 + threadIdx.x;      // over 2,560,000 uints
    if (i < NMROWS * 64) {
        const float2 v = *reinterpret_cast<const float2*>(&x[(size_t)i * 2]);
        xbf[i] = packbf2(v.x, v.y);
    }
}

// =============== message passing: 1 wave/node, ch-pair/lane, bf16 x ======
// hbf[c,n,:] = bf16( (1+eps)*x[c,n,:] + sum_j gelu(x[c,src]+emb_j)*emsk_j )
__global__ __launch_bounds__(256) void agg2_kernel(
    const uint32_t* __restrict__ xbf, // [4][N][64] planar packed bf16 pairs
    const uint32_t* __restrict__ embq,// [E][64] packed bf16 pairs
    const float4* __restrict__ emsk,  // [E] per-combo masks
    const int*   __restrict__ off,    // [N+1]
    const int*   __restrict__ esrc,   // [E] CSR src
    const float* __restrict__ epsp, int layer,
    uint32_t* __restrict__ hbf)       // [4][N][64] planar packed bf16
{
    const int lane = threadIdx.x & 63;
    const int wid  = threadIdx.x >> 6;
    const float epv = 1.0f + epsp[layer];

    for (int n = blockIdx.x * 4 + wid; n < NNODES; n += gridDim.x * 4) {
        const int j0 = off[n], j1 = off[n + 1];
        float acc[4][2] = {{0.f,0.f},{0.f,0.f},{0.f,0.f},{0.f,0.f}};

        // 1-deep software pipeline (proven structure)
        uint32_t eq_c = 0; uint32_t xu_c[4]; float4 em_c = {0,0,0,0};
        if (j0 < j1) {
            const int s = esrc[j0];
            eq_c = embq[(size_t)j0 * 64 + lane];
            em_c = emsk[j0];
            #pragma unroll
            for (int c = 0; c < 4; ++c)
                xu_c[c] = xbf[((size_t)c * NNODES + s) * 64 + lane];
        }
        for (int j = j0; j < j1; ++j) {
            const uint32_t eq = eq_c;
            const float4 em = em_c;
            uint32_t xu[4];
            #pragma unroll
            for (int c = 0; c < 4; ++c) xu[c] = xu_c[c];
            if (j + 1 < j1) {
                const int s = esrc[j + 1];
                eq_c = embq[(size_t)(j + 1) * 64 + lane];
                em_c = emsk[j + 1];
                #pragma unroll
                for (int c = 0; c < 4; ++c)
                    xu_c[c] = xbf[((size_t)c * NNODES + s) * 64 + lane];
            }
            const float e0 = bflo(eq);
            const float e1 = bfhi(eq);
            const float ms[4] = {em.x, em.y, em.z, em.w};
            #pragma unroll
            for (int c = 0; c < 4; ++c) {
                acc[c][0] += gelu_f(bflo(xu[c]) + e0) * ms[c];
                acc[c][1] += gelu_f(bfhi(xu[c]) + e1) * ms[c];
            }
        }
        #pragma unroll
        for (int c = 0; c < 4; ++c) {
            const uint32_t u = xbf[((size_t)c * NNODES + n) * 64 + lane];
            const float o0 = epv * bflo(u) + acc[c][0];
            const float o1 = epv * bfhi(u) + acc[c][1];
            hbf[((size_t)c * NNODES + n) * 64 + lane] = packbf2(o0, o1);
        }
    }
}

// ============ fallback agg (fp32 gather, bf16 h out) =====================
__global__ __launch_bounds__(256) void agg_kernel(
    const float* __restrict__ xcur, const float* __restrict__ nm,
    const float* __restrict__ ea_s, const float* __restrict__ bW,
    const float* __restrict__ bb, const int* __restrict__ off,
    const int* __restrict__ esrc, const float* __restrict__ epsp, int layer,
    short* __restrict__ hbf_s)
{
    const int tid = threadIdx.x;
    const int h   = tid & 127;
    const int sub = tid >> 7;
    float wc[16];
    #pragma unroll
    for (int k = 0; k < 16; ++k) wc[k] = bW[k * 128 + h];
    const float bbr = bb[h];
    const float epv = 1.0f + epsp[layer];

    for (int n = blockIdx.x * 2 + sub; n < NNODES; n += gridDim.x * 2) {
        float acc0 = 0.f, acc1 = 0.f, acc2 = 0.f, acc3 = 0.f;
        const int j0 = off[n], j1 = off[n + 1];
        const float d0 = nm[0*NNODES+n], d1 = nm[1*NNODES+n];
        const float d2 = nm[2*NNODES+n], d3 = nm[3*NNODES+n];
        for (int j = j0; j < j1; ++j) {
            const int src = esrc[j];
            const float4* eap = reinterpret_cast<const float4*>(ea_s + (size_t)j * 16);
            const float4 a0 = eap[0], a1 = eap[1], a2 = eap[2], a3 = eap[3];
            float emb = bbr;
            emb += a0.x*wc[0] + a0.y*wc[1] + a0.z*wc[2] + a0.w*wc[3];
            emb += a1.x*wc[4] + a1.y*wc[5] + a1.z*wc[6] + a1.w*wc[7];
            emb += a2.x*wc[8] + a2.y*wc[9] + a2.z*wc[10] + a2.w*wc[11];
            emb += a3.x*wc[12] + a3.y*wc[13] + a3.z*wc[14] + a3.w*wc[15];
            const float m0 = nm[0*NNODES+src]*d0, m1 = nm[1*NNODES+src]*d1;
            const float m2 = nm[2*NNODES+src]*d2, m3 = nm[3*NNODES+src]*d3;
            acc0 += gelu_f(xcur[((size_t)0*NNODES+src)*NH+h] + emb) * m0;
            acc1 += gelu_f(xcur[((size_t)1*NNODES+src)*NH+h] + emb) * m1;
            acc2 += gelu_f(xcur[((size_t)2*NNODES+src)*NH+h] + emb) * m2;
            acc3 += gelu_f(xcur[((size_t)3*NNODES+src)*NH+h] + emb) * m3;
        }
        hbf_s[((size_t)0*NNODES+n)*NH+h] = (short)f2bf_rne(epv * xcur[((size_t)0*NNODES+n)*NH+h] + acc0);
        hbf_s[((size_t)1*NNODES+n)*NH+h] = (short)f2bf_rne(epv * xcur[((size_t)1*NNODES+n)*NH+h] + acc1);
        hbf_s[((size_t)2*NNODES+n)*NH+h] = (short)f2bf_rne(epv * xcur[((size_t)2*NNODES+n)*NH+h] + acc2);
        hbf_s[((size_t)3*NNODES+n)*NH+h] = (short)f2bf_rne(epv * xcur[((size_t)3*NNODES+n)*NH+h] + acc3);
    }
}

// -------------------------------------------------------------------------
// MFMA fused conv pair (round-12 proven); h pre-packed bf16; emits fp32
// xcur + planar bf16 mirror (coalesced 2B stores).
// Fragments (16x16x32 bf16): A/B lane l: 8 contig k at (l>>4)*8; row/col l&15.
// C/D: col = l&15, row = (l>>4)*4 + reg  [m89-verified].
// -------------------------------------------------------------------------
__global__ __launch_bounds__(256) void conv_mfma_kernel(
    const uint32_t* __restrict__ hb,  // [40000][64] packed bf16
    const float* __restrict__ resid,  // [40000][128] fp32
    const short* __restrict__ W1t, const float* __restrict__ b1,
    const short* __restrict__ W2t, const float* __restrict__ b2,
    float* __restrict__ outp,         // [40000][128] fp32
    short* __restrict__ xb_s)         // [40000][128] bf16 mirror (planar)
{
    __shared__ short sh[FTILE * SSTR];
    __shared__ short st[FTILE * SSTR];
    __shared__ short sw[128 * SSTR];

    const int tid  = threadIdx.x;
    const int lane = tid & 63;
    const int w    = tid >> 6;
    const int l15  = lane & 15;
    const int l4   = lane >> 4;
    const int colb = w * 32;
    const int row0 = blockIdx.x * FTILE;

    for (int i = tid; i < FTILE * 16; i += 256) {
        const int r = i >> 4, c = i & 15;
        *reinterpret_cast<uint4*>(&sh[r * SSTR + c * 8]) =
            *reinterpret_cast<const uint4*>(&hb[(size_t)(row0 + r) * 64 + c * 4]);
    }
    for (int i = tid; i < 128 * 16; i += 256) {
        const int r = i >> 4, c = i & 15;
        *reinterpret_cast<uint4*>(&sw[r * SSTR + c * 8]) =
            *reinterpret_cast<const uint4*>(&W1t[r * 128 + c * 8]);
    }
    __syncthreads();

    f32x4 a00 = {0,0,0,0}, a01 = {0,0,0,0}, a10 = {0,0,0,0}, a11 = {0,0,0,0};
    #pragma unroll
    for (int s = 0; s < 4; ++s) {
        const int ko = s * 32 + l4 * 8;
        short8v fa0 = *reinterpret_cast<const short8v*>(&sh[(l15)      * SSTR + ko]);
        short8v fa1 = *reinterpret_cast<const short8v*>(&sh[(16 + l15) * SSTR + ko]);
        short8v fb0 = *reinterpret_cast<const short8v*>(&sw[(colb + l15)      * SSTR + ko]);
        short8v fb1 = *reinterpret_cast<const short8v*>(&sw[(colb + 16 + l15) * SSTR + ko]);
        a00 = __builtin_amdgcn_mfma_f32_16x16x32_bf16(fa0, fb0, a00, 0, 0, 0);
        a01 = __builtin_amdgcn_mfma_f32_16x16x32_bf16(fa0, fb1, a01, 0, 0, 0);
        a10 = __builtin_amdgcn_mfma_f32_16x16x32_bf16(fa1, fb0, a10, 0, 0, 0);
        a11 = __builtin_amdgcn_mfma_f32_16x16x32_bf16(fa1, fb1, a11, 0, 0, 0);
    }

    {
        const float bv0 = b1[colb + l15];
        const float bv1 = b1[colb + 16 + l15];
        #pragma unroll
        for (int j = 0; j < 4; ++j) {
            const int r0 = l4 * 4 + j;
            st[r0 * SSTR + colb + l15]             = (short)f2bf_rne(gelu_f(a00[j] + bv0));
            st[r0 * SSTR + colb + 16 + l15]        = (short)f2bf_rne(gelu_f(a01[j] + bv1));
            st[(16 + r0) * SSTR + colb + l15]      = (short)f2bf_rne(gelu_f(a10[j] + bv0));
            st[(16 + r0) * SSTR + colb + 16 + l15] = (short)f2bf_rne(gelu_f(a11[j] + bv1));
        }
    }
    __syncthreads();

    for (int i = tid; i < 128 * 16; i += 256) {
        const int r = i >> 4, c = i & 15;
        *reinterpret_cast<uint4*>(&sw[r * SSTR + c * 8]) =
            *reinterpret_cast<const uint4*>(&W2t[r * 128 + c * 8]);
    }
    __syncthreads();

    a00 = {0,0,0,0}; a01 = {0,0,0,0}; a10 = {0,0,0,0}; a11 = {0,0,0,0};
    #pragma unroll
    for (int s = 0; s < 4; ++s) {
        const int ko = s * 32 + l4 * 8;
        short8v fa0 = *reinterpret_cast<const short8v*>(&st[(l15)      * SSTR + ko]);
        short8v fa1 = *reinterpret_cast<const short8v*>(&st[(16 + l15) * SSTR + ko]);
        short8v fb0 = *reinterpret_cast<const short8v*>(&sw[(colb + l15)      * SSTR + ko]);
        short8v fb1 = *reinterpret_cast<const short8v*>(&sw[(colb + 16 + l15) * SSTR + ko]);
        a00 = __builtin_amdgcn_mfma_f32_16x16x32_bf16(fa0, fb0, a00, 0, 0, 0);
        a01 = __builtin_amdgcn_mfma_f32_16x16x32_bf16(fa0, fb1, a01, 0, 0, 0);
        a10 = __builtin_amdgcn_mfma_f32_16x16x32_bf16(fa1, fb0, a10, 0, 0, 0);
        a11 = __builtin_amdgcn_mfma_f32_16x16x32_bf16(fa1, fb1, a11, 0, 0, 0);
    }

    {
        const float bv0 = b2[colb + l15];
        const float bv1 = b2[colb + 16 + l15];
        #pragma unroll
        for (int j = 0; j < 4; ++j) {
            const int r0 = row0 + l4 * 4 + j;
            const int r1 = r0 + 16;
            const size_t o00 = (size_t)r0 * NH + colb + l15;
            const size_t o01 = (size_t)r0 * NH + colb + 16 + l15;
            const size_t o10 = (size_t)r1 * NH + colb + l15;
            const size_t o11 = (size_t)r1 * NH + colb + 16 + l15;
            const float v00 = resid[o00] + gelu_f(a00[j] + bv0);
            const float v01 = resid[o01] + gelu_f(a01[j] + bv1);
            const float v10 = resid[o10] + gelu_f(a10[j] + bv0);
            const float v11 = resid[o11] + gelu_f(a11[j] + bv1);
            outp[o00] = v00; xb_s[o00] = (short)f2bf_rne(v00);
            outp[o01] = v01; xb_s[o01] = (short)f2bf_rne(v01);
            outp[o10] = v10; xb_s[o10] = (short)f2bf_rne(v10);
            outp[o11] = v11; xb_s[o11] = (short)f2bf_rne(v11);
        }
    }
}

// -------------------------------------------------------------------------
// MFMA fused final MLP (round-12 proven): input from planar bf16 mirror.
// -------------------------------------------------------------------------
__global__ __launch_bounds__(256) void mlp_mfma_kernel(
    const uint32_t* __restrict__ xb,  // [40000][64] packed bf16
    const short* __restrict__ W1t, const float* __restrict__ b1,
    const short* __restrict__ W2t,    // [64 n][128 k] bf16
    const float* __restrict__ b2,     // [64]
    const float* __restrict__ nm,     // [40000]
    float* __restrict__ oacc)         // [256]
{
    __shared__ short sx[FTILE * SSTR];
    __shared__ short st[FTILE * SSTR];
    __shared__ short sw[128 * SSTR];
    __shared__ float sacc[256];

    const int tid  = threadIdx.x;
    const int lane = tid & 63;
    const int w    = tid >> 6;
    const int l15  = lane & 15;
    const int l4   = lane >> 4;
    const int colb = w * 32;
    const int row0 = blockIdx.x * FTILE;

    sacc[tid] = 0.0f;

    for (int i = tid; i < FTILE * 16; i += 256) {
        const int r = i >> 4, c = i & 15;
        *reinterpret_cast<uint4*>(&sx[r * SSTR + c * 8]) =
            *reinterpret_cast<const uint4*>(&xb[(size_t)(row0 + r) * 64 + c * 4]);
    }
    for (int i = tid; i < 128 * 16; i += 256) {
        const int r = i >> 4, c = i & 15;
        *reinterpret_cast<uint4*>(&sw[r * SSTR + c * 8]) =
            *reinterpret_cast<const uint4*>(&W1t[r * 128 + c * 8]);
    }
    __syncthreads();

    f32x4 a00 = {0,0,0,0}, a01 = {0,0,0,0}, a10 = {0,0,0,0}, a11 = {0,0,0,0};
    #pragma unroll
    for (int s = 0; s < 4; ++s) {
        const int ko = s * 32 + l4 * 8;
        short8v fa0 = *reinterpret_cast<const short8v*>(&sx[(l15)      * SSTR + ko]);
        short8v fa1 = *reinterpret_cast<const short8v*>(&sx[(16 + l15) * SSTR + ko]);
        short8v fb0 = *reinterpret_cast<const short8v*>(&sw[(colb + l15)      * SSTR + ko]);
        short8v fb1 = *reinterpret_cast<const short8v*>(&sw[(colb + 16 + l15) * SSTR + ko]);
        a00 = __builtin_amdgcn_mfma_f32_16x16x32_bf16(fa0, fb0, a00, 0, 0, 0);
        a01 = __builtin_amdgcn_mfma_f32_16x16x32_bf16(fa0, fb1, a01, 0, 0, 0);
        a10 = __builtin_amdgcn_mfma_f32_16x16x32_bf16(fa1, fb0, a10, 0, 0, 0);
        a11 = __builtin_amdgcn_mfma_f32_16x16x32_bf16(fa1, fb1, a11, 0, 0, 0);
    }

    {
        const float bv0 = b1[colb + l15];
        const float bv1 = b1[colb + 16 + l15];
        #pragma unroll
        for (int j = 0; j < 4; ++j) {
            const int r0 = l4 * 4 + j;
            st[r0 * SSTR + colb + l15]             = (short)f2bf_rne(fmaxf(a00[j] + bv0, 0.f));
            st[r0 * SSTR + colb + 16 + l15]        = (short)f2bf_rne(fmaxf(a01[j] + bv1, 0.f));
            st[(16 + r0) * SSTR + colb + l15]      = (short)f2bf_rne(fmaxf(a10[j] + bv0, 0.f));
            st[(16 + r0) * SSTR + colb + 16 + l15] = (short)f2bf_rne(fmaxf(a11[j] + bv1, 0.f));
        }
    }
    __syncthreads();

    for (int i = tid; i < 64 * 16; i += 256) {
        const int r = i >> 4, c = i & 15;
        *reinterpret_cast<uint4*>(&sw[r * SSTR + c * 8]) =
            *reinterpret_cast<const uint4*>(&W2t[r * 128 + c * 8]);
    }
    __syncthreads();

    const int colb2 = w * 16;
    f32x4 c0f = {0,0,0,0}, c1f = {0,0,0,0};
    #pragma unroll
    for (int s = 0; s < 4; ++s) {
        const int ko = s * 32 + l4 * 8;
        short8v fa0 = *reinterpret_cast<const short8v*>(&st[(l15)      * SSTR + ko]);
        short8v fa1 = *reinterpret_cast<const short8v*>(&st[(16 + l15) * SSTR + ko]);
        short8v fb  = *reinterpret_cast<const short8v*>(&sw[(colb2 + l15) * SSTR + ko]);
        c0f = __builtin_amdgcn_mfma_f32_16x16x32_bf16(fa0, fb, c0f, 0, 0, 0);
        c1f = __builtin_amdgcn_mfma_f32_16x16x32_bf16(fa1, fb, c1f, 0, 0, 0);
    }

    {
        const float bv = b2[colb2 + l15];
        #pragma unroll
        for (int j = 0; j < 4; ++j) {
            const int gr0 = row0 + l4 * 4 + j;
            const int gr1 = gr0 + 16;
            const float w0 = nm[gr0];
            const float w1 = nm[gr1];
            const int cb0 = gr0 / NNODES;
            const int cb1 = gr1 / NNODES;
            atomicAdd(&sacc[cb0 * 64 + colb2 + l15], (c0f[j] + bv) * w0);
            atomicAdd(&sacc[cb1 * 64 + colb2 + l15], (c1f[j] + bv) * w1);
        }
    }

    __syncthreads();
    atomicAdd(&oacc[tid], sacc[tid]);
}

// -------------------------------------------------------------------------
__global__ __launch_bounds__(256) void final_kernel(
    const float* __restrict__ acc, const float* __restrict__ nm,
    float* __restrict__ outp)
{
    const int tid  = threadIdx.x;
    const int c    = tid >> 6;
    const int lane = tid & 63;
    float s = 0.f;
    for (int n = lane; n < NNODES; n += 64) s += nm[c * NNODES + n];
    #pragma unroll
    for (int off = 32; off > 0; off >>= 1) s += __shfl_down(s, off, 64);
    const float denom = __shfl(s, 0, 64);
    outp[tid] = acc[tid] / denom;
}

extern "C" void kernel_launch(void* const* d_in, const int* in_sizes, int n_in,
                              void* d_out, int out_size, void* d_ws, size_t ws_size,
                              hipStream_t stream) {
    const float* x    = (const float*)d_in[0];
    const float* nm   = (const float*)d_in[1];
    const float* ea   = (const float*)d_in[2];
    const float* bW   = (const float*)d_in[3];
    const float* bb   = (const float*)d_in[4];
    const float* cW1  = (const float*)d_in[5];
    const float* cb1  = (const float*)d_in[6];
    const float* cW2  = (const float*)d_in[7];
    const float* cb2  = (const float*)d_in[8];
    const float* eps  = (const float*)d_in[9];
    const float* mW1  = (const float*)d_in[10];
    const float* mb1  = (const float*)d_in[11];
    const float* mW2  = (const float*)d_in[12];
    const float* mb2  = (const float*)d_in[13];
    const int*   ei   = (const int*)d_in[14];

    float* ws = (float*)d_ws;
    const bool big = ws_size >= (size_t)23230600ULL * 4ULL;   // ~93 MB

    if (big) {
        float*    xcur = ws;                           // 5,120,000
        float*    oacc = ws + 5120000;                 // 256
        uint32_t* hbf  = (uint32_t*)(ws + 5120512);    // 2,560,000 uints
        uint32_t* xbf  = (uint32_t*)(ws + 7680512);    // 2,560,000 uints (planar)
        float*    ea_s = ws + 10240512;                // 2,560,000 (dead after emb)
        short*    wbf  = (short*)ea_s;                 // 122,880 bf16 (aliases ea_s)
        float4*   emsk = (float4*)(ea_s + 61440);      // 160,000 float4 (aliases ea_s)
        uint32_t* embq = (uint32_t*)(ws + 12800512);   // 10,240,000 uints
        int*      ib   = (int*)(ws + 23040512);
        int* off = ib; int* cur = ib + 10002; int* deg = ib + 20002;
        int* esrc = ib + 30002;

        hipMemsetAsync(deg, 0, 10000 * 4, stream);
        hist_kernel<<<(NEDGES + 255) / 256, 256, 0, stream>>>(ei, deg);
        scan_kernel<<<1, 1024, 0, stream>>>(deg, off, cur);
        scatter_kernel<<<(NEDGES + 255) / 256, 256, 0, stream>>>(ei, ea, cur, esrc, ea_s);
        emb_kernel<<<10000, 256, 0, stream>>>(ea_s, bW, bb, embq);
        // ea_s region dead after emb: wbf + emsk alias it
        wtrans_kernel<<<480, 256, 0, stream>>>(cW1, cW2, mW1, mW2, wbf);
        emsk_kernel<<<(NNODES + 255) / 256, 256, 0, stream>>>(nm, off, esrc, emsk);
        xcast_kernel<<<10000, 256, 0, stream>>>(x, xbf);

        for (int l = 0; l < 3; ++l) {
            const float* resid = (l == 0) ? x : xcur;
            agg2_kernel<<<2500, 256, 0, stream>>>(xbf, embq, emsk, off, esrc,
                                                  eps, l, hbf);
            conv_mfma_kernel<<<FTILES, 256, 0, stream>>>(hbf, resid,
                wbf + (size_t)l * 16384, cb1 + l * 128,
                wbf + (size_t)(3 + l) * 16384, cb2 + l * 128,
                xcur, (short*)xbf);
        }
        hipMemsetAsync(oacc, 0, 256 * 4, stream);
        mlp_mfma_kernel<<<FTILES, 256, 0, stream>>>(xbf, wbf + 98304, mb1,
                                                    wbf + 114688, mb2, nm, oacc);
        final_kernel<<<1, 256, 0, stream>>>(oacc, nm, (float*)d_out);
    } else {
        // fallback (~52.3 MB): fp32-gather agg + MFMA conv/mlp
        float*    xcur = ws;                           // 5,120,000
        float*    oacc = ws + 5120000;                 // 256
        uint32_t* hbf  = (uint32_t*)(ws + 5120512);    // 2,560,000 uints
        uint32_t* xbf  = (uint32_t*)(ws + 7680512);    // 2,560,000 uints
        float*    ea_s = ws + 10240512;                // 2,560,000
        int*      ib   = (int*)(ws + 12800512);
        int* off = ib; int* cur = ib + 10002; int* deg = ib + 20002;
        int* esrc = ib + 30002;
        short* wbf = (short*)(ib + 190004);            // 122,880 shorts

        hipMemcpyAsync(xcur, x, (size_t)5120000 * 4, hipMemcpyDeviceToDevice, stream);
        hipMemsetAsync(deg, 0, 10000 * 4, stream);
        hist_kernel<<<(NEDGES + 255) / 256, 256, 0, stream>>>(ei, deg);
        scan_kernel<<<1, 1024, 0, stream>>>(deg, off, cur);
        scatter_kernel<<<(NEDGES + 255) / 256, 256, 0, stream>>>(ei, ea, cur, esrc, ea_s);
        wtrans_kernel<<<480, 256, 0, stream>>>(cW1, cW2, mW1, mW2, wbf);

        for (int l = 0; l < 3; ++l) {
            const float* resid = (l == 0) ? x : xcur;
            agg_kernel<<<2500, 256, 0, stream>>>(xcur, nm, ea_s, bW, bb, off, esrc,
                                                 eps, l, (short*)hbf);
            conv_mfma_kernel<<<FTILES, 256, 0, stream>>>(hbf, resid,
                wbf + (size_t)l * 16384, cb1 + l * 128,
                wbf + (size_t)(3 + l) * 16384, cb2 + l * 128,
                xcur, (short*)xbf);
        }
        hipMemsetAsync(oacc, 0, 256 * 4, stream);
        mlp_mfma_kernel<<<FTILES, 256, 0, stream>>>(xbf, wbf + 98304, mb1,
                                                    wbf + 114688, mb2, nm, oacc);
        final_kernel<<<1, 256, 0, stream>>>(oacc, nm, (float*)d_out);
    }
}